// Round 2
// baseline (384.957 us; speedup 1.0000x reference)
//
#include <hip/hip_runtime.h>
#include <math.h>

// Problem constants (fixed by setup_inputs)
#define DD 128
#define NROWS 769          // 256 input-enc + 256 output-enc + 256 gate + 1 zero
#define T_TOTAL 524288

typedef float vfloat4 __attribute__((ext_vector_type(4)));

// ws layout (floats):
//   table [NROWS][DD]   @ 0
//   Psrc  [NROWS][DD]   @ NROWS*DD
//   Pdst  [NROWS][DD]   @ 2*NROWS*DD
//   Prel  [2][DD]       @ 3*NROWS*DD
// total = 3*769*128 + 256 = 295552 floats = ~1.18 MB

__global__ void build_table(const float* __restrict__ gate_emb,
                            float* __restrict__ table) {
    int row = blockIdx.x;      // 0..768
    int j = threadIdx.x;       // 0..127
    float v;
    if (row < 512) {
        int p = row & 255;     // position (input/output tables are identical)
        int i = j >> 1;        // pair index 0..63
        float div = expf(-logf(10000.0f) * (2.0f * (float)i) / 128.0f);
        float ang = (float)p * div;
        v = (j & 1) ? cosf(ang) : sinf(ang);
    } else if (row < 768) {
        v = gate_emb[(row - 512) * DD + j];
    } else {
        v = 0.0f;
    }
    table[row * DD + j] = v;
}

// One block per table row; thread j computes dot(row, W[j, part]) for the
// src part (cols 0..127) and dst part (cols 256..383) of W [128 x 384].
__global__ void precompute_nodes(const float* __restrict__ table,
                                 const float* __restrict__ W,
                                 float* __restrict__ Psrc,
                                 float* __restrict__ Pdst) {
    __shared__ float row[DD];
    int r = blockIdx.x;
    int j = threadIdx.x;
    row[j] = table[r * DD + j];
    __syncthreads();
    const float* wj = W + j * 384;
    float s = 0.0f, d = 0.0f;
#pragma unroll 8
    for (int k = 0; k < DD; ++k) {
        float e = row[k];               // LDS broadcast (free)
        s = fmaf(e, wj[k], s);
        d = fmaf(e, wj[256 + k], d);
    }
    Psrc[r * DD + j] = s;
    Pdst[r * DD + j] = d;
}

// Prel[r] = W[:,128:256] . edge_emb[r] + b   (2 rows)
__global__ void precompute_rel(const float* __restrict__ edge_emb,
                               const float* __restrict__ W,
                               const float* __restrict__ b,
                               float* __restrict__ Prel) {
    __shared__ float row[DD];
    int r = blockIdx.x;       // 0..1
    int j = threadIdx.x;
    row[j] = edge_emb[r * DD + j];
    __syncthreads();
    const float* wj = W + j * 384 + 128;
    float s = b[j];
#pragma unroll 8
    for (int k = 0; k < DD; ++k) s = fmaf(row[k], wj[k], s);
    Prel[r * DD + j] = s;
}

// out[t] = Psrc[fs(t)] + Prel[rel(t)] + Pdst[fd(t)]
// 32 lanes per row (float4 each), 8 rows per 256-thread block.
__global__ __launch_bounds__(256) void gather_add(
    const int* __restrict__ src_idx, const int* __restrict__ src_type,
    const int* __restrict__ rel, const int* __restrict__ dst_idx,
    const int* __restrict__ dst_type,
    const vfloat4* __restrict__ Psrc, const vfloat4* __restrict__ Pdst,
    const vfloat4* __restrict__ Prel, vfloat4* __restrict__ out) {
    int tid = threadIdx.x;
    int lane = tid & 31;                       // which float4 of the 128-dim row
    int rowInBlk = tid >> 5;
    int t = blockIdx.x * 8 + rowInBlk;

    int st = src_type[t];
    int si = src_idx[t];
    int dt = dst_type[t];
    int di = dst_idx[t];
    int rl = rel[t];

    int fs = (st == 3) ? 768 : st * 256 + si;  // offsets {0,256,512}, zero row 768
    int fd = (dt == 3) ? 768 : dt * 256 + di;

    vfloat4 a = Psrc[fs * 32 + lane];
    vfloat4 r4 = Prel[rl * 32 + lane];
    vfloat4 c = Pdst[fd * 32 + lane];
    vfloat4 o = a + r4 + c;
    // Nontemporal: don't let the 256MB output stream evict the hot P-tables in L2.
    __builtin_nontemporal_store(o, &out[t * 32 + lane]);
}

extern "C" void kernel_launch(void* const* d_in, const int* in_sizes, int n_in,
                              void* d_out, int out_size, void* d_ws, size_t ws_size,
                              hipStream_t stream) {
    const float* gate_emb = (const float*)d_in[0];
    const float* edge_emb = (const float*)d_in[1];
    const float* W        = (const float*)d_in[2];
    const float* b        = (const float*)d_in[3];
    const int* src_idx    = (const int*)d_in[4];
    const int* src_type   = (const int*)d_in[5];
    const int* rel        = (const int*)d_in[6];
    const int* dst_idx    = (const int*)d_in[7];
    const int* dst_type   = (const int*)d_in[8];
    // d_in[9], d_in[10]: num_input_nodes / num_output_nodes == 256 (fixed)

    float* ws    = (float*)d_ws;
    float* table = ws;
    float* Psrc  = ws + NROWS * DD;
    float* Pdst  = ws + 2 * NROWS * DD;
    float* Prel  = ws + 3 * NROWS * DD;

    build_table<<<NROWS, DD, 0, stream>>>(gate_emb, table);
    precompute_nodes<<<NROWS, DD, 0, stream>>>(table, W, Psrc, Pdst);
    precompute_rel<<<2, DD, 0, stream>>>(edge_emb, W, b, Prel);

    gather_add<<<T_TOTAL / 8, 256, 0, stream>>>(
        src_idx, src_type, rel, dst_idx, dst_type,
        (const vfloat4*)Psrc, (const vfloat4*)Pdst, (const vfloat4*)Prel,
        (vfloat4*)d_out);
}

// Round 3
// 370.882 us; speedup vs baseline: 1.0380x; 1.0380x over previous
//
#include <hip/hip_runtime.h>
#include <math.h>

// Problem constants (fixed by setup_inputs)
#define DD 128
#define NROWS 769          // 256 input-enc + 256 output-enc + 256 gate + 1 zero
#define T_TOTAL 524288

typedef float vfloat4 __attribute__((ext_vector_type(4)));

// ws layout (floats):
//   Wt      [3][128][128] @ 0          (Wt[part][k][j] = W[j][part*128+k])
//   Psrc    [NROWS][DD]   @ 49152
//   Pdst    [NROWS][DD]   @ 49152 +  98432
//   Prel    [2][DD]       @ 49152 + 196864
// total ~= 246272 floats ~= 0.99 MB (fits easily in ws)

#define WT_OFF    0
#define PSRC_OFF  (3 * DD * DD)
#define PDST_OFF  (PSRC_OFF + NROWS * DD)
#define PREL_OFF  (PDST_OFF + NROWS * DD)

// Transpose W (128 x 384, row-major) into three 128x128 column-major-ish
// blocks so the precompute loop reads coalesced along j.
__global__ void transposeW(const float* __restrict__ W, float* __restrict__ Wt) {
    int k = blockIdx.x;    // 0..127
    int j = threadIdx.x;   // 0..127
    Wt[0 * DD * DD + k * DD + j] = W[j * 384 + k];         // src part
    Wt[1 * DD * DD + k * DD + j] = W[j * 384 + 128 + k];   // rel part
    Wt[2 * DD * DD + k * DD + j] = W[j * 384 + 256 + k];   // dst part
}

// One block per table row (769 node rows + 2 rel rows). Builds the embedding
// row in LDS, then computes the W projection with coalesced Wt reads.
__global__ __launch_bounds__(DD) void prep(
    const float* __restrict__ gate_emb, const float* __restrict__ edge_emb,
    const float* __restrict__ b, const float* __restrict__ Wt,
    float* __restrict__ Psrc, float* __restrict__ Pdst,
    float* __restrict__ Prel) {
    __shared__ float row[DD];
    int r = blockIdx.x;
    int j = threadIdx.x;

    if (r < NROWS) {
        float v;
        if (r < 512) {
            int p = r & 255;   // input/output sinusoid tables are identical
            int i = j >> 1;
            float div = expf(-logf(10000.0f) * (2.0f * (float)i) / 128.0f);
            float ang = (float)p * div;
            v = (j & 1) ? cosf(ang) : sinf(ang);
        } else if (r < 768) {
            v = gate_emb[(r - 512) * DD + j];
        } else {
            v = 0.0f;
        }
        row[j] = v;
        __syncthreads();
        const float* Ws = Wt;                 // src part
        const float* Wd = Wt + 2 * DD * DD;   // dst part
        float s = 0.0f, d = 0.0f;
#pragma unroll 8
        for (int k = 0; k < DD; ++k) {
            float e = row[k];                          // LDS broadcast (free)
            s = fmaf(e, Ws[k * DD + j], s);            // coalesced
            d = fmaf(e, Wd[k * DD + j], d);
        }
        Psrc[r * DD + j] = s;
        Pdst[r * DD + j] = d;
    } else {
        int rr = r - NROWS;                   // 0..1
        row[j] = edge_emb[rr * DD + j];
        __syncthreads();
        const float* Wr = Wt + 1 * DD * DD;   // rel part
        float s = b[j];
#pragma unroll 8
        for (int k = 0; k < DD; ++k) s = fmaf(row[k], Wr[k * DD + j], s);
        Prel[rr * DD + j] = s;
    }
}

// out[t] = Psrc[fs(t)] + Prel[rel(t)] + Pdst[fd(t)]
// 32 lanes per row (float4 each), 8 rows per 256-thread block.
__global__ __launch_bounds__(256) void gather_add(
    const int* __restrict__ src_idx, const int* __restrict__ src_type,
    const int* __restrict__ rel, const int* __restrict__ dst_idx,
    const int* __restrict__ dst_type,
    const vfloat4* __restrict__ Psrc, const vfloat4* __restrict__ Pdst,
    const vfloat4* __restrict__ Prel, vfloat4* __restrict__ out) {
    int tid = threadIdx.x;
    int lane = tid & 31;                       // which float4 of the 128-dim row
    int rowInBlk = tid >> 5;
    int t = blockIdx.x * 8 + rowInBlk;

    int st = src_type[t];
    int si = src_idx[t];
    int dt = dst_type[t];
    int di = dst_idx[t];
    int rl = rel[t];

    int fs = (st == 3) ? 768 : st * 256 + si;  // offsets {0,256,512}, zero row 768
    int fd = (dt == 3) ? 768 : dt * 256 + di;

    vfloat4 a = Psrc[fs * 32 + lane];
    vfloat4 r4 = Prel[rl * 32 + lane];
    vfloat4 c = Pdst[fd * 32 + lane];
    vfloat4 o = a + r4 + c;
    // Nontemporal: don't let the 256MB output stream evict the hot P-tables in L2.
    __builtin_nontemporal_store(o, &out[t * 32 + lane]);
}

extern "C" void kernel_launch(void* const* d_in, const int* in_sizes, int n_in,
                              void* d_out, int out_size, void* d_ws, size_t ws_size,
                              hipStream_t stream) {
    const float* gate_emb = (const float*)d_in[0];
    const float* edge_emb = (const float*)d_in[1];
    const float* W        = (const float*)d_in[2];
    const float* b        = (const float*)d_in[3];
    const int* src_idx    = (const int*)d_in[4];
    const int* src_type   = (const int*)d_in[5];
    const int* rel        = (const int*)d_in[6];
    const int* dst_idx    = (const int*)d_in[7];
    const int* dst_type   = (const int*)d_in[8];
    // d_in[9], d_in[10]: num_input_nodes / num_output_nodes == 256 (fixed)

    float* ws   = (float*)d_ws;
    float* Wt   = ws + WT_OFF;
    float* Psrc = ws + PSRC_OFF;
    float* Pdst = ws + PDST_OFF;
    float* Prel = ws + PREL_OFF;

    transposeW<<<DD, DD, 0, stream>>>(W, Wt);
    prep<<<NROWS + 2, DD, 0, stream>>>(gate_emb, edge_emb, b, Wt,
                                       Psrc, Pdst, Prel);
    gather_add<<<T_TOTAL / 8, 256, 0, stream>>>(
        src_idx, src_type, rel, dst_idx, dst_type,
        (const vfloat4*)Psrc, (const vfloat4*)Pdst, (const vfloat4*)Prel,
        (vfloat4*)d_out);
}